// Round 6
// baseline (316.093 us; speedup 1.0000x reference)
//
#include <hip/hip_runtime.h>
#include <cstddef>

#define NQ 2048    // batch B
#define NS 20000   // stars N
#define NSP 20032  // NS padded to 64
#define DD 64      // feature dim
#define DY 32      // label dim
#define LL 100     // unique labels
#define NT 313     // i-tiles of 64 (NSP/64)
#define PSTR 72    // P-tile LDS row stride in shorts (conflict-free for b64 W / b128 R)
#define LOG2E 1.4426950408889634f
#define NELD (-0.01f * 1.4426950408889634f)  // -eta*log2e

typedef __attribute__((ext_vector_type(8))) short bfrag;   // 8 bf16 (A/B operand)
typedef __attribute__((ext_vector_type(4))) float ffrag;   // 4 f32  (C/D operand)

#if __has_builtin(__builtin_amdgcn_exp2f)
#define EXP2(x) __builtin_amdgcn_exp2f(x)
#else
#define EXP2(x) exp2f(x)
#endif

#define MFMA __builtin_amdgcn_mfma_f32_16x16x32_bf16

__device__ __forceinline__ unsigned short bf16rne(float v) {
  unsigned int u = __float_as_uint(v);
  u += 0x7FFFu + ((u >> 16) & 1u);
  return (unsigned short)(u >> 16);
}

__device__ __forceinline__ uint4 pack8(const unsigned short* o) {
  uint4 q;
  q.x = (unsigned int)o[0] | ((unsigned int)o[1] << 16);
  q.y = (unsigned int)o[2] | ((unsigned int)o[3] << 16);
  q.z = (unsigned int)o[4] | ((unsigned int)o[5] << 16);
  q.w = (unsigned int)o[6] | ((unsigned int)o[7] << 16);
  return q;
}

// ---------------- k_prep: blocks [0,NT): tile converts/norms/transposes; [NT,NT+8): x-side ----------------
__global__ __launch_bounds__(256) void k_prep(
    const float* __restrict__ star, const float* __restrict__ f1,
    const float* __restrict__ f2, const float* __restrict__ slab,
    const float* __restrict__ x,
    const int* __restrict__ lidx1, const int* __restrict__ lidx2,
    unsigned short* __restrict__ star_b, unsigned short* __restrict__ f1_rm,
    unsigned short* __restrict__ f2_rm, unsigned short* __restrict__ vt1,
    unsigned short* __restrict__ vt2, unsigned short* __restrict__ xb,
    float* __restrict__ nsl, float* __restrict__ nf1l, float* __restrict__ nf2l,
    float* __restrict__ nxl, int* __restrict__ lidxp1, int* __restrict__ lidxp2,
    int* __restrict__ matchIdx)
{
  __shared__ float tile[64][65];
  const int tid = threadIdx.x;
  if (blockIdx.x >= NT) {  // ---- prepB: xb = bf16(x*2log2e), nxl, matchIdx ----
    int b = (blockIdx.x - NT) * 256 + tid;
    if (b >= NQ) return;
    const float* px = x + (size_t)b * DD;
    float s = 0.f;
    for (int d = 0; d < DD; d += 4) {
      float4 v = *(const float4*)(px + d);
      s += v.x*v.x + v.y*v.y + v.z*v.z + v.w*v.w;
      unsigned int lo = (unsigned int)bf16rne(v.x * (2.f * LOG2E)) |
                        ((unsigned int)bf16rne(v.y * (2.f * LOG2E)) << 16);
      unsigned int hi = (unsigned int)bf16rne(v.z * (2.f * LOG2E)) |
                        ((unsigned int)bf16rne(v.w * (2.f * LOG2E)) << 16);
      *(uint2*)(xb + (size_t)b * DD + d) = make_uint2(lo, hi);
    }
    nxl[b] = LOG2E * s;
    matchIdx[b] = NS;
    return;
  }
  const int i0 = blockIdx.x * 64;
  const int r = tid >> 2, cs = (tid & 3) * 16;
  const int dT = tid >> 2, is = (tid & 3) * 16;
  const bool okr = (i0 + r) < NS;

  const float* srcs[3] = {star, f1, f2};
  unsigned short* dsts[3] = {star_b, f1_rm, f2_rm};
  float* norms[3] = {nsl, nf1l, nf2l};
#pragma unroll 1
  for (int a = 0; a < 3; a++) {
    float v[16];
    const float* src = srcs[a] + (size_t)(i0 + r) * DD + cs;
#pragma unroll
    for (int q = 0; q < 4; q++) {
      float4 t4 = okr ? *(const float4*)(src + q * 4) : make_float4(0.f, 0.f, 0.f, 0.f);
      v[4*q+0] = t4.x; v[4*q+1] = t4.y; v[4*q+2] = t4.z; v[4*q+3] = t4.w;
    }
    unsigned short ob[16];
#pragma unroll
    for (int j = 0; j < 16; j++) { ob[j] = bf16rne(v[j]); tile[r][cs + j] = v[j]; }
    *(uint4*)(dsts[a] + (size_t)(i0 + r) * DD + cs) = pack8(ob);
    *(uint4*)(dsts[a] + (size_t)(i0 + r) * DD + cs + 8) = pack8(ob + 8);
    __syncthreads();
    if (tid < 64) {
      float s = 0.f;
      for (int d = 0; d < DD; d++) s += tile[tid][d] * tile[tid][d];
      norms[a][i0 + tid] = (i0 + tid) < NS ? LOG2E * s : 1e30f;
    }
    if (a > 0) {  // vt1 rows: a==1 -> 0..63 (f1^T), a==2 -> 64..127 (f2^T)
      unsigned short tb[16];
#pragma unroll
      for (int j = 0; j < 16; j++) tb[j] = bf16rne(tile[is + j][dT]);
      unsigned short* dst = vt1 + (size_t)((a - 1) * DD + dT) * NSP + i0 + is;
      *(uint4*)dst = pack8(tb);
      *(uint4*)(dst + 8) = pack8(tb + 8);
    }
    __syncthreads();
  }

  // slab (64 x 32) -> vt2 rows 0..31
  if (tid < 128) {
    const int r2 = tid >> 1, cs2 = (tid & 1) * 16;
    const bool ok2 = (i0 + r2) < NS;
    const float* src = slab + (size_t)(i0 + r2) * DY + cs2;
#pragma unroll
    for (int q = 0; q < 4; q++) {
      float4 t4 = ok2 ? *(const float4*)(src + q * 4) : make_float4(0.f, 0.f, 0.f, 0.f);
      tile[r2][cs2+4*q+0] = t4.x; tile[r2][cs2+4*q+1] = t4.y;
      tile[r2][cs2+4*q+2] = t4.z; tile[r2][cs2+4*q+3] = t4.w;
    }
  }
  __syncthreads();
  if (tid < 128) {
    const int d2 = tid >> 2, is2 = (tid & 3) * 16;
    unsigned short tb[16];
#pragma unroll
    for (int j = 0; j < 16; j++) tb[j] = bf16rne(tile[is2 + j][d2]);
    unsigned short* dst = vt2 + (size_t)d2 * NSP + i0 + is2;
    *(uint4*)dst = pack8(tb);
    *(uint4*)(dst + 8) = pack8(tb + 8);
  }
  if (tid < 64) {
    int i = i0 + tid;
    bool ok = i < NS;
    lidxp1[i] = ok ? lidx1[i] : 0;
    lidxp2[i] = ok ? lidx2[i] : 0;
  }
}

// ---------------- K1: pipelined flash-style e_star pass, 64i x 32b per wave ----------------
// Steady state per tile t: [prefetch A(t+1)] [exp/pack/ds_write(t) || G1-MFMA(t+1)] [ds_read P(t)] [G2(t)]
__global__ __launch_bounds__(128, 2) void k_star(
    const unsigned short* __restrict__ xb, const unsigned short* __restrict__ star_b,
    const unsigned short* __restrict__ vt1, const float* __restrict__ nsl,
    const float* __restrict__ nxl,
    float* __restrict__ xtp, float* __restrict__ sump,
    int* __restrict__ matchIdx, int nch)
{
  __shared__ __align__(16) unsigned short plds[2][32 * PSTR];
  const int w = threadIdx.x >> 6, lane = threadIdx.x & 63;
  const int col = lane & 15, quad = lane >> 4;
  const int b0 = blockIdx.x * 64 + w * 32;
  const int k = blockIdx.y;
  const int t0 = (k * NT) / nch, t1 = ((k + 1) * NT) / nch;
  unsigned short* myp = &plds[w][0];

  bfrag xq00 = *(const bfrag*)(xb + (size_t)(b0 + col) * DD + quad * 8);
  bfrag xq01 = *(const bfrag*)(xb + (size_t)(b0 + col) * DD + 32 + quad * 8);
  bfrag xq10 = *(const bfrag*)(xb + (size_t)(b0 + 16 + col) * DD + quad * 8);
  bfrag xq11 = *(const bfrag*)(xb + (size_t)(b0 + 16 + col) * DD + 32 + quad * 8);
  const float nx0 = nxl[b0 + col], nx1 = nxl[b0 + 16 + col];

  ffrag acc[8][2];
#pragma unroll
  for (int n = 0; n < 8; n++) {
    acc[n][0] = (ffrag){0.f, 0.f, 0.f, 0.f};
    acc[n][1] = (ffrag){0.f, 0.f, 0.f, 0.f};
  }
  float es0 = 0.f, es1 = 0.f;
  int lmin0 = NS, lmin1 = NS;

  // prologue: G1(t0)
  ffrag cf[4][2];
#pragma unroll
  for (int m = 0; m < 4; m++) {
    const unsigned short* ap = star_b + (size_t)(t0 * 64 + m * 16 + col) * DD + quad * 8;
    bfrag a0 = *(const bfrag*)(ap);
    bfrag a1 = *(const bfrag*)(ap + 32);
    ffrag c0 = (ffrag){0.f, 0.f, 0.f, 0.f};
    ffrag c1 = (ffrag){0.f, 0.f, 0.f, 0.f};
    c0 = MFMA(a0, xq00, c0, 0, 0, 0); c0 = MFMA(a1, xq01, c0, 0, 0, 0);
    c1 = MFMA(a0, xq10, c1, 0, 0, 0); c1 = MFMA(a1, xq11, c1, 0, 0, 0);
    cf[m][0] = c0; cf[m][1] = c1;
  }

  for (int t = t0; t < t1; ++t) {
    const int i0 = t * 64;
    const bool more = (t + 1 < t1);
    const int tn = more ? t + 1 : t;
    // prefetch A(t+1)
    bfrag an[4][2];
#pragma unroll
    for (int m = 0; m < 4; m++) {
      const unsigned short* ap = star_b + (size_t)(tn * 64 + m * 16 + col) * DD + quad * 8;
      an[m][0] = *(const bfrag*)(ap);
      an[m][1] = *(const bfrag*)(ap + 32);
    }
    // exp/pack/write(t) interleaved with G1(t+1)
#pragma unroll
    for (int m = 0; m < 4; m++) {
      float4 nsv = *(const float4*)(nsl + i0 + m * 16 + quad * 4);
      float nsa[4] = {nsv.x, nsv.y, nsv.z, nsv.w};
      const int ibase = i0 + m * 16 + quad * 4;
      unsigned short p0[4], p1[4];
#pragma unroll
      for (int r = 0; r < 4; r++) {
        float g0 = cf[m][0][r] - nsa[r];
        float g1 = cf[m][1][r] - nsa[r];
        if (g0 >= nx0) lmin0 = min(lmin0, ibase + r);
        if (g1 >= nx1) lmin1 = min(lmin1, ibase + r);
        float e0 = EXP2(g0), e1 = EXP2(g1);
        es0 += e0; es1 += e1;
        p0[r] = bf16rne(e0); p1[r] = bf16rne(e1);
      }
      *(uint2*)(myp + col * PSTR + m * 16 + quad * 4) =
          make_uint2((unsigned)p0[0] | ((unsigned)p0[1] << 16),
                     (unsigned)p0[2] | ((unsigned)p0[3] << 16));
      *(uint2*)(myp + (col + 16) * PSTR + m * 16 + quad * 4) =
          make_uint2((unsigned)p1[0] | ((unsigned)p1[1] << 16),
                     (unsigned)p1[2] | ((unsigned)p1[3] << 16));
      if (more) {
        ffrag c0 = (ffrag){0.f, 0.f, 0.f, 0.f};
        ffrag c1 = (ffrag){0.f, 0.f, 0.f, 0.f};
        c0 = MFMA(an[m][0], xq00, c0, 0, 0, 0); c0 = MFMA(an[m][1], xq01, c0, 0, 0, 0);
        c1 = MFMA(an[m][0], xq10, c1, 0, 0, 0); c1 = MFMA(an[m][1], xq11, c1, 0, 0, 0);
        cf[m][0] = c0; cf[m][1] = c1;
      }
    }
    // read P(t) (per-wave in-order DS: no barrier, single buffer safe)
    bfrag pa0 = *(const bfrag*)(myp + col * PSTR + quad * 8);
    bfrag pa1 = *(const bfrag*)(myp + col * PSTR + 32 + quad * 8);
    bfrag pb0 = *(const bfrag*)(myp + (col + 16) * PSTR + quad * 8);
    bfrag pb1 = *(const bfrag*)(myp + (col + 16) * PSTR + 32 + quad * 8);
    // G2(t)
#pragma unroll
    for (int n = 0; n < 8; n++) {
      const unsigned short* vp = vt1 + (size_t)(n * 16 + col) * NSP + i0 + quad * 8;
      bfrag v0 = *(const bfrag*)(vp);
      bfrag v1 = *(const bfrag*)(vp + 32);
      acc[n][0] = MFMA(pa0, v0, acc[n][0], 0, 0, 0);
      acc[n][0] = MFMA(pa1, v1, acc[n][0], 0, 0, 0);
      acc[n][1] = MFMA(pb0, v0, acc[n][1], 0, 0, 0);
      acc[n][1] = MFMA(pb1, v1, acc[n][1], 0, 0, 0);
    }
  }

#pragma unroll
  for (int h = 0; h < 2; h++)
#pragma unroll
    for (int n = 0; n < 8; n++)
#pragma unroll
      for (int r = 0; r < 4; r++) {
        int b = b0 + h * 16 + quad * 4 + r;
        xtp[((size_t)k * NQ + b) * 128 + n * 16 + col] = acc[n][h][r];
      }
  es0 += __shfl_xor(es0, 16, 64); es0 += __shfl_xor(es0, 32, 64);
  es1 += __shfl_xor(es1, 16, 64); es1 += __shfl_xor(es1, 32, 64);
  if (quad == 0) {
    sump[(size_t)k * NQ + b0 + col] = es0;
    sump[(size_t)k * NQ + b0 + 16 + col] = es1;
  }
  if (lmin0 < NS) atomicMin(matchIdx + b0 + col, lmin0);
  if (lmin1 < NS) atomicMin(matchIdx + b0 + 16 + col, lmin1);
}

// ---------------- K2: reduce partials -> xt, xtb, y, y_idx, lgP tables ----------------
__global__ __launch_bounds__(256) void k_mid(
    const float* __restrict__ xtp, const float* __restrict__ sump,
    const int* __restrict__ matchIdx,
    const float* __restrict__ f1, const float* __restrict__ f2,
    const float* __restrict__ W1, const float* __restrict__ b1,
    const float* __restrict__ W2, const float* __restrict__ b2,
    const float* __restrict__ u1, const float* __restrict__ u2,
    const float* __restrict__ ld1, const float* __restrict__ ld2,
    unsigned short* __restrict__ xtb1, unsigned short* __restrict__ xtb2,
    int* __restrict__ yid1, int* __restrict__ yid2,
    float* __restrict__ lgP1f, float* __restrict__ lgP2f, int nch)
{
  __shared__ float xts[2][4][64];
  __shared__ float ys[4][64];
  __shared__ int yids[2][4];
  const int lane = threadIdx.x & 63;
  const int w = __builtin_amdgcn_readfirstlane(threadIdx.x >> 6);
  const int b = blockIdx.x * 4 + w;

  float s1 = 0.f, s2 = 0.f, S = 0.f;
  for (int kk = 0; kk < nch; kk++) {
    const float* row = xtp + ((size_t)kk * NQ + b) * 128;
    s1 += row[lane];
    s2 += row[64 + lane];
    S  += sump[(size_t)kk * NQ + b];
  }
  const int m = matchIdx[b];
  float xa, xb_;
  if (m < NS) {
    xa = f1[(size_t)m * DD + lane];
    xb_ = f2[(size_t)m * DD + lane];
  } else {
    xa = s1 / S;
    xb_ = s2 / S;
  }
  xtb1[(size_t)b * DD + lane] = bf16rne(xa * (2.f * LOG2E));
  xtb2[(size_t)b * DD + lane] = bf16rne(xb_ * (2.f * LOG2E));
  xts[0][w][lane] = xa;
  xts[1][w][lane] = xb_;
  __syncthreads();

  const int half = lane >> 5;
  const int j = lane & 31;
  const float* W = half ? W2 : W1;
  float y = (half ? b2 : b1)[j];
  for (int d = 0; d < DD; d++) y += xts[half][w][d] * W[d * DY + j];
  ys[w][lane] = y;
  __syncthreads();

#pragma unroll
  for (int p = 0; p < 2; p++) {
    const float* u = p ? u2 : u1;
    unsigned long long best = ~0ull;
#pragma unroll
    for (int h = 0; h < 2; h++) {
      int l = lane + h * 64;
      if (l < LL) {
        float dist = 0.f;
        for (int jj = 0; jj < DY; jj++) {
          float diff = ys[w][p * 32 + jj] - u[(size_t)l * DY + jj];
          dist += diff * diff;
        }
        unsigned long long pk = ((unsigned long long)__float_as_uint(dist) << 32) | (unsigned)l;
        best = best < pk ? best : pk;
      }
    }
#pragma unroll
    for (int off = 32; off > 0; off >>= 1) {
      unsigned long long o = __shfl_xor(best, off, 64);
      best = best < o ? best : o;
    }
    if (lane == 0) {
      int yy = (int)(best & 0xffffffffull);
      (p ? yid2 : yid1)[b] = yy;
      yids[p][w] = yy;
    }
  }
  __syncthreads();
  // fill lgP tables for this block's 4 queries: lgP[(l*64+bb)*16+c] float2 {b, b+16}
  for (int idx = threadIdx.x; idx < 2 * LL * 4; idx += 256) {
    int p = idx >= LL * 4;
    int rem = idx - p * LL * 4;
    int l = rem >> 2, w2 = rem & 3;
    int bq = blockIdx.x * 4 + w2;
    float val = NELD * (p ? ld2 : ld1)[l * LL + yids[p][w2]];
    int bb = bq >> 5, c = bq & 15, hf = (bq >> 4) & 1;
    (p ? lgP2f : lgP1f)[(((size_t)l * 64 + bb) * 16 + c) * 2 + hf] = val;
  }
}

// ---------------- K3: pipelined flash-style e2 pass, both branches (z) ----------------
__global__ __launch_bounds__(128, 2) void k_out(
    const unsigned short* __restrict__ xtb1, const unsigned short* __restrict__ xtb2,
    const unsigned short* __restrict__ f1_rm, const unsigned short* __restrict__ f2_rm,
    const unsigned short* __restrict__ vt2,
    const float* __restrict__ nf1l, const float* __restrict__ nf2l,
    const int* __restrict__ lidxp1, const int* __restrict__ lidxp2,
    const float2* __restrict__ lgP1, const float2* __restrict__ lgP2,
    float* __restrict__ qp1, float* __restrict__ qp2,
    float* __restrict__ qsp1, float* __restrict__ qsp2, int nch)
{
  __shared__ __align__(16) unsigned short plds[2][32 * PSTR];
  const int br = blockIdx.z;
  const unsigned short* xtb = br ? xtb2 : xtb1;
  const unsigned short* f_rm = br ? f2_rm : f1_rm;
  const float* nfl = br ? nf2l : nf1l;
  const int* lidxp = br ? lidxp2 : lidxp1;
  const float2* lgP = br ? lgP2 : lgP1;
  float* qp = br ? qp2 : qp1;
  float* qsp = br ? qsp2 : qsp1;

  const int w = threadIdx.x >> 6, lane = threadIdx.x & 63;
  const int col = lane & 15, quad = lane >> 4;
  const int b0 = blockIdx.x * 64 + w * 32;
  const int bb = blockIdx.x * 2 + w;
  const int k = blockIdx.y;
  const int t0 = (k * NT) / nch, t1 = ((k + 1) * NT) / nch;
  unsigned short* myp = &plds[w][0];

  bfrag xq00 = *(const bfrag*)(xtb + (size_t)(b0 + col) * DD + quad * 8);
  bfrag xq01 = *(const bfrag*)(xtb + (size_t)(b0 + col) * DD + 32 + quad * 8);
  bfrag xq10 = *(const bfrag*)(xtb + (size_t)(b0 + 16 + col) * DD + quad * 8);
  bfrag xq11 = *(const bfrag*)(xtb + (size_t)(b0 + 16 + col) * DD + 32 + quad * 8);

  ffrag acc[2][2];
#pragma unroll
  for (int n = 0; n < 2; n++) {
    acc[n][0] = (ffrag){0.f, 0.f, 0.f, 0.f};
    acc[n][1] = (ffrag){0.f, 0.f, 0.f, 0.f};
  }
  float es0 = 0.f, es1 = 0.f;

  // prologue: lv(t0), G1(t0)
  int4 lvr[4];
  ffrag cf[4][2];
#pragma unroll
  for (int m = 0; m < 4; m++) {
    lvr[m] = *(const int4*)(lidxp + t0 * 64 + m * 16 + quad * 4);
    const unsigned short* ap = f_rm + (size_t)(t0 * 64 + m * 16 + col) * DD + quad * 8;
    bfrag a0 = *(const bfrag*)(ap);
    bfrag a1 = *(const bfrag*)(ap + 32);
    ffrag c0 = (ffrag){0.f, 0.f, 0.f, 0.f};
    ffrag c1 = (ffrag){0.f, 0.f, 0.f, 0.f};
    c0 = MFMA(a0, xq00, c0, 0, 0, 0); c0 = MFMA(a1, xq01, c0, 0, 0, 0);
    c1 = MFMA(a0, xq10, c1, 0, 0, 0); c1 = MFMA(a1, xq11, c1, 0, 0, 0);
    cf[m][0] = c0; cf[m][1] = c1;
  }

  for (int t = t0; t < t1; ++t) {
    const int i0 = t * 64;
    const bool more = (t + 1 < t1);
    const int tn = more ? t + 1 : t;
    // eld gathers for t (lv prefetched last iter)
    float2 gv[4][4];
#pragma unroll
    for (int m = 0; m < 4; m++) {
      int la[4] = {lvr[m].x, lvr[m].y, lvr[m].z, lvr[m].w};
#pragma unroll
      for (int r = 0; r < 4; r++)
        gv[m][r] = lgP[((size_t)la[r] * 64 + bb) * 16 + col];
    }
    // prefetch lv(t+1), A(t+1)
    bfrag an[4][2];
#pragma unroll
    for (int m = 0; m < 4; m++) {
      lvr[m] = *(const int4*)(lidxp + tn * 64 + m * 16 + quad * 4);
      const unsigned short* ap = f_rm + (size_t)(tn * 64 + m * 16 + col) * DD + quad * 8;
      an[m][0] = *(const bfrag*)(ap);
      an[m][1] = *(const bfrag*)(ap + 32);
    }
    // exp/pack/write(t) interleaved with G1(t+1)
#pragma unroll
    for (int m = 0; m < 4; m++) {
      float4 nfv = *(const float4*)(nfl + i0 + m * 16 + quad * 4);
      float nfa[4] = {nfv.x, nfv.y, nfv.z, nfv.w};
      unsigned short p0[4], p1[4];
#pragma unroll
      for (int r = 0; r < 4; r++) {
        float e0 = EXP2(cf[m][0][r] - nfa[r] + gv[m][r].x);
        float e1 = EXP2(cf[m][1][r] - nfa[r] + gv[m][r].y);
        es0 += e0; es1 += e1;
        p0[r] = bf16rne(e0); p1[r] = bf16rne(e1);
      }
      *(uint2*)(myp + col * PSTR + m * 16 + quad * 4) =
          make_uint2((unsigned)p0[0] | ((unsigned)p0[1] << 16),
                     (unsigned)p0[2] | ((unsigned)p0[3] << 16));
      *(uint2*)(myp + (col + 16) * PSTR + m * 16 + quad * 4) =
          make_uint2((unsigned)p1[0] | ((unsigned)p1[1] << 16),
                     (unsigned)p1[2] | ((unsigned)p1[3] << 16));
      if (more) {
        ffrag c0 = (ffrag){0.f, 0.f, 0.f, 0.f};
        ffrag c1 = (ffrag){0.f, 0.f, 0.f, 0.f};
        c0 = MFMA(an[m][0], xq00, c0, 0, 0, 0); c0 = MFMA(an[m][1], xq01, c0, 0, 0, 0);
        c1 = MFMA(an[m][0], xq10, c1, 0, 0, 0); c1 = MFMA(an[m][1], xq11, c1, 0, 0, 0);
        cf[m][0] = c0; cf[m][1] = c1;
      }
    }
    // read P(t), G2(t)
    bfrag pa0 = *(const bfrag*)(myp + col * PSTR + quad * 8);
    bfrag pa1 = *(const bfrag*)(myp + col * PSTR + 32 + quad * 8);
    bfrag pb0 = *(const bfrag*)(myp + (col + 16) * PSTR + quad * 8);
    bfrag pb1 = *(const bfrag*)(myp + (col + 16) * PSTR + 32 + quad * 8);
#pragma unroll
    for (int n = 0; n < 2; n++) {
      const unsigned short* vp = vt2 + (size_t)(n * 16 + col) * NSP + i0 + quad * 8;
      bfrag v0 = *(const bfrag*)(vp);
      bfrag v1 = *(const bfrag*)(vp + 32);
      acc[n][0] = MFMA(pa0, v0, acc[n][0], 0, 0, 0);
      acc[n][0] = MFMA(pa1, v1, acc[n][0], 0, 0, 0);
      acc[n][1] = MFMA(pb0, v0, acc[n][1], 0, 0, 0);
      acc[n][1] = MFMA(pb1, v1, acc[n][1], 0, 0, 0);
    }
  }

#pragma unroll
  for (int h = 0; h < 2; h++)
#pragma unroll
    for (int n = 0; n < 2; n++)
#pragma unroll
      for (int r = 0; r < 4; r++) {
        int b = b0 + h * 16 + quad * 4 + r;
        qp[((size_t)k * NQ + b) * DY + n * 16 + col] = acc[n][h][r];
      }
  es0 += __shfl_xor(es0, 16, 64); es0 += __shfl_xor(es0, 32, 64);
  es1 += __shfl_xor(es1, 16, 64); es1 += __shfl_xor(es1, 32, 64);
  if (quad == 0) {
    qsp[(size_t)k * NQ + b0 + col] = es0;
    qsp[(size_t)k * NQ + b0 + 16 + col] = es1;
  }
}

// ---------------- K4: reduce partials + average ----------------
__global__ __launch_bounds__(256) void k_fin(
    const float* __restrict__ qp1, const float* __restrict__ qsp1,
    const float* __restrict__ qp2, const float* __restrict__ qsp2,
    float* __restrict__ out, int nch)
{
  int t = blockIdx.x * 256 + threadIdx.x;
  if (t >= NQ * DY) return;
  int b = t >> 5, j = t & 31;
  float n1 = 0.f, d1 = 0.f, n2 = 0.f, d2 = 0.f;
  for (int kk = 0; kk < nch; kk++) {
    n1 += qp1[((size_t)kk * NQ + b) * DY + j];
    n2 += qp2[((size_t)kk * NQ + b) * DY + j];
    d1 += qsp1[(size_t)kk * NQ + b];
    d2 += qsp2[(size_t)kk * NQ + b];
  }
  out[t] = 0.5f * (n1 / d1 + n2 / d2);
}

extern "C" void kernel_launch(void* const* d_in, const int* in_sizes, int n_in,
                              void* d_out, int out_size, void* d_ws, size_t ws_size,
                              hipStream_t stream)
{
  const float* x    = (const float*)d_in[0];
  const float* star = (const float*)d_in[1];
  const float* slab = (const float*)d_in[2];
  const float* f1   = (const float*)d_in[3];
  const float* f2   = (const float*)d_in[4];
  const float* u1   = (const float*)d_in[5];
  const float* u2   = (const float*)d_in[6];
  const float* ld1  = (const float*)d_in[7];
  const float* ld2  = (const float*)d_in[8];
  const float* W1   = (const float*)d_in[9];
  const float* b1   = (const float*)d_in[10];
  const float* W2   = (const float*)d_in[11];
  const float* b2   = (const float*)d_in[12];
  const int* lidx1  = (const int*)d_in[13];
  const int* lidx2  = (const int*)d_in[14];
  float* out = (float*)d_out;

  auto al = [](size_t b) { return (b + 255) & ~(size_t)255; };
  const size_t auxBytes =
      al((size_t)NQ * DD * 2) +           // xb
      3 * al((size_t)NSP * DD * 2) +      // star_b, f1_rm, f2_rm
      al((size_t)128 * NSP * 2) +         // vt1
      al((size_t)32 * NSP * 2) +          // vt2
      2 * al((size_t)NQ * DD * 2) +       // xtb1/2
      3 * al((size_t)NSP * 4) +           // nsl,nf1l,nf2l
      al((size_t)NQ * 4) +                // nxl
      2 * al((size_t)LL * 64 * 16 * 8) +  // lgP1/2
      2 * al((size_t)NSP * 4) +           // lidxp1/2
      3 * al((size_t)NQ * 4);             // matchIdx, yid1, yid2
  const size_t pc1 = (size_t)NQ * 4 * 129;           // xtp + sump per chunk
  const size_t pc2 = (size_t)NQ * 4 * 2 * (DY + 1);  // qp1/2 + qsp1/2 per chunk
  int nch1 = 48, nch2 = 48;
  while ((nch1 > 6) && auxBytes + nch1 * pc1 + nch2 * pc2 > ws_size) {
    nch1 >>= 1;
    if (nch2 > 6) nch2 >>= 1;
  }

  char* base = (char*)d_ws;
  size_t off = 0;
  auto alloc = [&](size_t bytes) -> char* {
    char* p = base + off;
    off = (off + bytes + 255) & ~(size_t)255;
    return p;
  };
  float* xtp  = (float*)alloc((size_t)nch1 * NQ * 128 * 4);
  float* sump = (float*)alloc((size_t)nch1 * NQ * 4);
  float* qp1  = (float*)alloc((size_t)nch2 * NQ * DY * 4);
  float* qp2  = (float*)alloc((size_t)nch2 * NQ * DY * 4);
  float* qsp1 = (float*)alloc((size_t)nch2 * NQ * 4);
  float* qsp2 = (float*)alloc((size_t)nch2 * NQ * 4);
  unsigned short* xb     = (unsigned short*)alloc((size_t)NQ * DD * 2);
  unsigned short* star_b = (unsigned short*)alloc((size_t)NSP * DD * 2);
  unsigned short* f1_rm  = (unsigned short*)alloc((size_t)NSP * DD * 2);
  unsigned short* f2_rm  = (unsigned short*)alloc((size_t)NSP * DD * 2);
  unsigned short* vt1    = (unsigned short*)alloc((size_t)128 * NSP * 2);
  unsigned short* vt2    = (unsigned short*)alloc((size_t)32 * NSP * 2);
  unsigned short* xtb1   = (unsigned short*)alloc((size_t)NQ * DD * 2);
  unsigned short* xtb2   = (unsigned short*)alloc((size_t)NQ * DD * 2);
  float* nsl   = (float*)alloc(NSP * 4);
  float* nf1l  = (float*)alloc(NSP * 4);
  float* nf2l  = (float*)alloc(NSP * 4);
  float* nxl   = (float*)alloc(NQ * 4);
  float2* lgP1 = (float2*)alloc((size_t)LL * 64 * 16 * 8);
  float2* lgP2 = (float2*)alloc((size_t)LL * 64 * 16 * 8);
  int* lidxp1 = (int*)alloc(NSP * 4);
  int* lidxp2 = (int*)alloc(NSP * 4);
  int* matchIdx = (int*)alloc(NQ * 4);
  int* yid1 = (int*)alloc(NQ * 4);
  int* yid2 = (int*)alloc(NQ * 4);

  k_prep<<<NT + (NQ + 255) / 256, 256, 0, stream>>>(
      star, f1, f2, slab, x, lidx1, lidx2,
      star_b, f1_rm, f2_rm, vt1, vt2, xb,
      nsl, nf1l, nf2l, nxl, lidxp1, lidxp2, matchIdx);

  k_star<<<dim3(NQ / 64, nch1), 128, 0, stream>>>(
      xb, star_b, vt1, nsl, nxl, xtp, sump, matchIdx, nch1);

  k_mid<<<NQ / 4, 256, 0, stream>>>(
      xtp, sump, matchIdx, f1, f2, W1, b1, W2, b2, u1, u2, ld1, ld2,
      xtb1, xtb2, yid1, yid2, (float*)lgP1, (float*)lgP2, nch1);

  k_out<<<dim3(NQ / 64, nch2, 2), 128, 0, stream>>>(
      xtb1, xtb2, f1_rm, f2_rm, vt2, nf1l, nf2l, lidxp1, lidxp2,
      lgP1, lgP2, qp1, qp2, qsp1, qsp2, nch2);

  k_fin<<<(NQ * DY + 255) / 256, 256, 0, stream>>>(qp1, qsp1, qp2, qsp2, out, nch2);
}

// Round 7
// 226.735 us; speedup vs baseline: 1.3941x; 1.3941x over previous
//
#include <hip/hip_runtime.h>
#include <cstddef>

#define NQ 2048    // batch B
#define NS 20000   // stars N
#define NSP 20032  // NS padded to 64
#define DD 64      // feature dim
#define DY 32      // label dim
#define LL 100     // unique labels
#define NT 313     // i-tiles of 64 (NSP/64)
#define PSTR 72    // P-tile LDS row stride in shorts (conflict-free b64 W / b128 R)
#define LOG2E 1.4426950408889634f
#define NELD (-0.01f * 1.4426950408889634f)  // -eta*log2e

typedef __attribute__((ext_vector_type(8))) short bfrag;   // 8 bf16 (A/B operand)
typedef __attribute__((ext_vector_type(4))) float ffrag;   // 4 f32  (C/D operand)

#if __has_builtin(__builtin_amdgcn_exp2f)
#define EXP2(x) __builtin_amdgcn_exp2f(x)
#else
#define EXP2(x) exp2f(x)
#endif

#define MFMA __builtin_amdgcn_mfma_f32_16x16x32_bf16

// async global->LDS DMA, 16 B/lane; LDS dest = uniform base + lane*16
#define GLOAD_LDS(gp, lp)                                                       \
  __builtin_amdgcn_global_load_lds(                                             \
      (const __attribute__((address_space(1))) unsigned int*)(gp),              \
      (__attribute__((address_space(3))) unsigned int*)(lp), 16, 0, 0)

__device__ __forceinline__ unsigned short bf16rne(float v) {
  unsigned int u = __float_as_uint(v);
  u += 0x7FFFu + ((u >> 16) & 1u);
  return (unsigned short)(u >> 16);
}

__device__ __forceinline__ uint4 pack8(const unsigned short* o) {
  uint4 q;
  q.x = (unsigned int)o[0] | ((unsigned int)o[1] << 16);
  q.y = (unsigned int)o[2] | ((unsigned int)o[3] << 16);
  q.z = (unsigned int)o[4] | ((unsigned int)o[5] << 16);
  q.w = (unsigned int)o[6] | ((unsigned int)o[7] << 16);
  return q;
}

// ---------------- k_prep: blocks [0,NT): tile converts/norms/transposes; [NT,..): x-side ----------------
__global__ __launch_bounds__(256) void k_prep(
    const float* __restrict__ star, const float* __restrict__ f1,
    const float* __restrict__ f2, const float* __restrict__ slab,
    const float* __restrict__ x,
    const int* __restrict__ lidx1, const int* __restrict__ lidx2,
    unsigned short* __restrict__ star_b, unsigned short* __restrict__ f1_rm,
    unsigned short* __restrict__ f2_rm, unsigned short* __restrict__ vt1,
    unsigned short* __restrict__ vt2, unsigned short* __restrict__ xb,
    float* __restrict__ nsl, float* __restrict__ nf1l, float* __restrict__ nf2l,
    float* __restrict__ nxl, int* __restrict__ lidxp1, int* __restrict__ lidxp2,
    int* __restrict__ matchIdx)
{
  __shared__ float tile[64][65];
  const int tid = threadIdx.x;
  if (blockIdx.x >= NT) {  // x-side: xb = bf16(x*2log2e), nxl, matchIdx
    int b = (blockIdx.x - NT) * 256 + tid;
    if (b >= NQ) return;
    const float* px = x + (size_t)b * DD;
    float s = 0.f;
    for (int d = 0; d < DD; d += 4) {
      float4 v = *(const float4*)(px + d);
      s += v.x*v.x + v.y*v.y + v.z*v.z + v.w*v.w;
      unsigned int lo = (unsigned int)bf16rne(v.x * (2.f * LOG2E)) |
                        ((unsigned int)bf16rne(v.y * (2.f * LOG2E)) << 16);
      unsigned int hi = (unsigned int)bf16rne(v.z * (2.f * LOG2E)) |
                        ((unsigned int)bf16rne(v.w * (2.f * LOG2E)) << 16);
      *(uint2*)(xb + (size_t)b * DD + d) = make_uint2(lo, hi);
    }
    nxl[b] = LOG2E * s;
    matchIdx[b] = NS;
    return;
  }
  const int i0 = blockIdx.x * 64;
  const int r = tid >> 2, cs = (tid & 3) * 16;
  const int dT = tid >> 2, is = (tid & 3) * 16;
  const bool okr = (i0 + r) < NS;

  const float* srcs[3] = {star, f1, f2};
  unsigned short* dsts[3] = {star_b, f1_rm, f2_rm};
  float* norms[3] = {nsl, nf1l, nf2l};
#pragma unroll 1
  for (int a = 0; a < 3; a++) {
    float v[16];
    const float* src = srcs[a] + (size_t)(i0 + r) * DD + cs;
#pragma unroll
    for (int q = 0; q < 4; q++) {
      float4 t4 = okr ? *(const float4*)(src + q * 4) : make_float4(0.f, 0.f, 0.f, 0.f);
      v[4*q+0] = t4.x; v[4*q+1] = t4.y; v[4*q+2] = t4.z; v[4*q+3] = t4.w;
    }
    unsigned short ob[16];
#pragma unroll
    for (int j = 0; j < 16; j++) { ob[j] = bf16rne(v[j]); tile[r][cs + j] = v[j]; }
    *(uint4*)(dsts[a] + (size_t)(i0 + r) * DD + cs) = pack8(ob);
    *(uint4*)(dsts[a] + (size_t)(i0 + r) * DD + cs + 8) = pack8(ob + 8);
    __syncthreads();
    if (tid < 64) {
      float s = 0.f;
      for (int d = 0; d < DD; d++) s += tile[tid][d] * tile[tid][d];
      norms[a][i0 + tid] = (i0 + tid) < NS ? LOG2E * s : 1e30f;
    }
    if (a > 0) {  // vt1 rows: a==1 -> 0..63 (f1^T), a==2 -> 64..127 (f2^T)
      unsigned short tb[16];
#pragma unroll
      for (int j = 0; j < 16; j++) tb[j] = bf16rne(tile[is + j][dT]);
      unsigned short* dst = vt1 + (size_t)((a - 1) * DD + dT) * NSP + i0 + is;
      *(uint4*)dst = pack8(tb);
      *(uint4*)(dst + 8) = pack8(tb + 8);
    }
    __syncthreads();
  }

  // slab (64 x 32) -> vt2 rows 0..31
  if (tid < 128) {
    const int r2 = tid >> 1, cs2 = (tid & 1) * 16;
    const bool ok2 = (i0 + r2) < NS;
    const float* src = slab + (size_t)(i0 + r2) * DY + cs2;
#pragma unroll
    for (int q = 0; q < 4; q++) {
      float4 t4 = ok2 ? *(const float4*)(src + q * 4) : make_float4(0.f, 0.f, 0.f, 0.f);
      tile[r2][cs2+4*q+0] = t4.x; tile[r2][cs2+4*q+1] = t4.y;
      tile[r2][cs2+4*q+2] = t4.z; tile[r2][cs2+4*q+3] = t4.w;
    }
  }
  __syncthreads();
  if (tid < 128) {
    const int d2 = tid >> 2, is2 = (tid & 3) * 16;
    unsigned short tb[16];
#pragma unroll
    for (int j = 0; j < 16; j++) tb[j] = bf16rne(tile[is2 + j][d2]);
    unsigned short* dst = vt2 + (size_t)d2 * NSP + i0 + is2;
    *(uint4*)dst = pack8(tb);
    *(uint4*)(dst + 8) = pack8(tb + 8);
  }
  if (tid < 64) {
    int i = i0 + tid;
    bool ok = i < NS;
    lidxp1[i] = ok ? lidx1[i] : 0;
    lidxp2[i] = ok ? lidx2[i] : 0;
  }
}

// ---------------- K1: e_star pass, block-staged tiles (m97 pattern) ----------------
// Block = 256 thr (4 waves x 32 b-cols = 128 b). Per tile: DMA-stage A(8KB)+vt1(16KB)
// into swizzled LDS, barrier, G1 from LDS -> exp -> P(LDS, wave-private) -> G2 from LDS, barrier.
__global__ __launch_bounds__(256, 3) void k_star(
    const unsigned short* __restrict__ xb, const unsigned short* __restrict__ star_b,
    const unsigned short* __restrict__ vt1, const float* __restrict__ nsl,
    const float* __restrict__ nxl,
    float* __restrict__ xtp, float* __restrict__ sump,
    int* __restrict__ matchIdx, int nch)
{
  __shared__ __align__(16) unsigned short sm[4096 + 8192 + 4 * 32 * PSTR];  // A | vt | P
  unsigned short* aT = sm;
  unsigned short* vT = sm + 4096;
  const int tid = threadIdx.x;
  const int w = tid >> 6, lane = tid & 63;
  const int col = lane & 15, quad = lane >> 4;
  const int x0s = quad ^ (col & 7);        // swizzled chunk for k-frag 0
  const int x1s = x0s ^ 4;                 // k-frag 1
  unsigned short* myp = sm + 4096 + 8192 + w * (32 * PSTR);
  const int b0 = blockIdx.x * 128 + w * 32;
  const int k = blockIdx.y;
  const int t0 = (k * NT) / nch, t1 = ((k + 1) * NT) / nch;

  bfrag xq00 = *(const bfrag*)(xb + (size_t)(b0 + col) * DD + quad * 8);
  bfrag xq01 = *(const bfrag*)(xb + (size_t)(b0 + col) * DD + 32 + quad * 8);
  bfrag xq10 = *(const bfrag*)(xb + (size_t)(b0 + 16 + col) * DD + quad * 8);
  bfrag xq11 = *(const bfrag*)(xb + (size_t)(b0 + 16 + col) * DD + 32 + quad * 8);
  const float nx0 = nxl[b0 + col], nx1 = nxl[b0 + 16 + col];

  ffrag acc[8][2];
#pragma unroll
  for (int n = 0; n < 8; n++) {
    acc[n][0] = (ffrag){0.f, 0.f, 0.f, 0.f};
    acc[n][1] = (ffrag){0.f, 0.f, 0.f, 0.f};
  }
  float es0 = 0.f, es1 = 0.f;
  int lmin0 = NS, lmin1 = NS;

  for (int t = t0; t < t1; ++t) {
    const int i0 = t * 64;
    // ---- stage: A 2 instr/wave, vt 4 instr/wave (swizzled chunks) ----
#pragma unroll
    for (int j = 0; j < 2; j++) {
      int S = ((w * 2 + j) << 6) + lane;
      int r = S >> 3, cs = S & 7;
      GLOAD_LDS(star_b + (size_t)(i0 + r) * DD + ((cs ^ (r & 7)) << 3),
                aT + ((w * 2 + j) << 9));
    }
#pragma unroll
    for (int j = 0; j < 4; j++) {
      int S = ((w * 4 + j) << 6) + lane;
      int r = S >> 3, cs = S & 7;
      GLOAD_LDS(vt1 + (size_t)r * NSP + i0 + ((cs ^ (r & 7)) << 3),
                vT + ((w * 4 + j) << 9));
    }
    __syncthreads();
    // ---- G1 + exp + P-write ----
#pragma unroll
    for (int m = 0; m < 4; m++) {
      const int row = m * 16 + col;
      bfrag a0 = *(const bfrag*)(aT + row * 64 + x0s * 8);
      bfrag a1 = *(const bfrag*)(aT + row * 64 + x1s * 8);
      ffrag c0 = (ffrag){0.f, 0.f, 0.f, 0.f};
      ffrag c1 = (ffrag){0.f, 0.f, 0.f, 0.f};
      c0 = MFMA(a0, xq00, c0, 0, 0, 0); c0 = MFMA(a1, xq01, c0, 0, 0, 0);
      c1 = MFMA(a0, xq10, c1, 0, 0, 0); c1 = MFMA(a1, xq11, c1, 0, 0, 0);
      float4 nsv = *(const float4*)(nsl + i0 + m * 16 + quad * 4);
      float nsa[4] = {nsv.x, nsv.y, nsv.z, nsv.w};
      const int ibase = i0 + m * 16 + quad * 4;
      unsigned short p0[4], p1[4];
#pragma unroll
      for (int r = 0; r < 4; r++) {
        float g0 = c0[r] - nsa[r];
        float g1 = c1[r] - nsa[r];
        if (g0 >= nx0) lmin0 = min(lmin0, ibase + r);
        if (g1 >= nx1) lmin1 = min(lmin1, ibase + r);
        float e0 = EXP2(g0), e1 = EXP2(g1);
        es0 += e0; es1 += e1;
        p0[r] = bf16rne(e0); p1[r] = bf16rne(e1);
      }
      *(uint2*)(myp + col * PSTR + m * 16 + quad * 4) =
          make_uint2((unsigned)p0[0] | ((unsigned)p0[1] << 16),
                     (unsigned)p0[2] | ((unsigned)p0[3] << 16));
      *(uint2*)(myp + (col + 16) * PSTR + m * 16 + quad * 4) =
          make_uint2((unsigned)p1[0] | ((unsigned)p1[1] << 16),
                     (unsigned)p1[2] | ((unsigned)p1[3] << 16));
    }
    // ---- P-read (wave-private, in-order DS) + G2 from staged vt ----
    bfrag pa0 = *(const bfrag*)(myp + col * PSTR + quad * 8);
    bfrag pa1 = *(const bfrag*)(myp + col * PSTR + 32 + quad * 8);
    bfrag pb0 = *(const bfrag*)(myp + (col + 16) * PSTR + quad * 8);
    bfrag pb1 = *(const bfrag*)(myp + (col + 16) * PSTR + 32 + quad * 8);
#pragma unroll
    for (int n = 0; n < 8; n++) {
      const int row = n * 16 + col;
      bfrag v0 = *(const bfrag*)(vT + row * 64 + x0s * 8);
      bfrag v1 = *(const bfrag*)(vT + row * 64 + x1s * 8);
      acc[n][0] = MFMA(pa0, v0, acc[n][0], 0, 0, 0);
      acc[n][0] = MFMA(pa1, v1, acc[n][0], 0, 0, 0);
      acc[n][1] = MFMA(pb0, v0, acc[n][1], 0, 0, 0);
      acc[n][1] = MFMA(pb1, v1, acc[n][1], 0, 0, 0);
    }
    __syncthreads();
  }

#pragma unroll
  for (int h = 0; h < 2; h++)
#pragma unroll
    for (int n = 0; n < 8; n++)
#pragma unroll
      for (int r = 0; r < 4; r++) {
        int b = b0 + h * 16 + quad * 4 + r;
        xtp[((size_t)k * NQ + b) * 128 + n * 16 + col] = acc[n][h][r];
      }
  es0 += __shfl_xor(es0, 16, 64); es0 += __shfl_xor(es0, 32, 64);
  es1 += __shfl_xor(es1, 16, 64); es1 += __shfl_xor(es1, 32, 64);
  if (quad == 0) {
    sump[(size_t)k * NQ + b0 + col] = es0;
    sump[(size_t)k * NQ + b0 + 16 + col] = es1;
  }
  if (lmin0 < NS) atomicMin(matchIdx + b0 + col, lmin0);
  if (lmin1 < NS) atomicMin(matchIdx + b0 + 16 + col, lmin1);
}

// ---------------- K2: reduce partials -> xt, xtb, y, y_idx, lgP tables ----------------
__global__ __launch_bounds__(256) void k_mid(
    const float* __restrict__ xtp, const float* __restrict__ sump,
    const int* __restrict__ matchIdx,
    const float* __restrict__ f1, const float* __restrict__ f2,
    const float* __restrict__ W1, const float* __restrict__ b1,
    const float* __restrict__ W2, const float* __restrict__ b2,
    const float* __restrict__ u1, const float* __restrict__ u2,
    const float* __restrict__ ld1, const float* __restrict__ ld2,
    unsigned short* __restrict__ xtb1, unsigned short* __restrict__ xtb2,
    int* __restrict__ yid1, int* __restrict__ yid2,
    float* __restrict__ lgP1f, float* __restrict__ lgP2f, int nch)
{
  __shared__ float xts[2][4][64];
  __shared__ float ys[4][64];
  __shared__ int yids[2][4];
  const int lane = threadIdx.x & 63;
  const int w = __builtin_amdgcn_readfirstlane(threadIdx.x >> 6);
  const int b = blockIdx.x * 4 + w;

  float s1 = 0.f, s2 = 0.f, S = 0.f;
  for (int kk = 0; kk < nch; kk++) {
    const float* row = xtp + ((size_t)kk * NQ + b) * 128;
    s1 += row[lane];
    s2 += row[64 + lane];
    S  += sump[(size_t)kk * NQ + b];
  }
  const int m = matchIdx[b];
  float xa, xb_;
  if (m < NS) {
    xa = f1[(size_t)m * DD + lane];
    xb_ = f2[(size_t)m * DD + lane];
  } else {
    xa = s1 / S;
    xb_ = s2 / S;
  }
  xtb1[(size_t)b * DD + lane] = bf16rne(xa * (2.f * LOG2E));
  xtb2[(size_t)b * DD + lane] = bf16rne(xb_ * (2.f * LOG2E));
  xts[0][w][lane] = xa;
  xts[1][w][lane] = xb_;
  __syncthreads();

  const int half = lane >> 5;
  const int j = lane & 31;
  const float* W = half ? W2 : W1;
  float y = (half ? b2 : b1)[j];
  for (int d = 0; d < DD; d++) y += xts[half][w][d] * W[d * DY + j];
  ys[w][lane] = y;
  __syncthreads();

#pragma unroll
  for (int p = 0; p < 2; p++) {
    const float* u = p ? u2 : u1;
    unsigned long long best = ~0ull;
#pragma unroll
    for (int h = 0; h < 2; h++) {
      int l = lane + h * 64;
      if (l < LL) {
        float dist = 0.f;
        for (int jj = 0; jj < DY; jj++) {
          float diff = ys[w][p * 32 + jj] - u[(size_t)l * DY + jj];
          dist += diff * diff;
        }
        unsigned long long pk = ((unsigned long long)__float_as_uint(dist) << 32) | (unsigned)l;
        best = best < pk ? best : pk;
      }
    }
#pragma unroll
    for (int off = 32; off > 0; off >>= 1) {
      unsigned long long o = __shfl_xor(best, off, 64);
      best = best < o ? best : o;
    }
    if (lane == 0) {
      int yy = (int)(best & 0xffffffffull);
      (p ? yid2 : yid1)[b] = yy;
      yids[p][w] = yy;
    }
  }
  __syncthreads();
  // lgP[(l*64+bb)*16+c] float2 {col, col+16} for this block's 4 queries
  for (int idx = threadIdx.x; idx < 2 * LL * 4; idx += 256) {
    int p = idx >= LL * 4;
    int rem = idx - p * LL * 4;
    int l = rem >> 2, w2 = rem & 3;
    int bq = blockIdx.x * 4 + w2;
    float val = NELD * (p ? ld2 : ld1)[l * LL + yids[p][w2]];
    int bb = bq >> 5, c = bq & 15, hf = (bq >> 4) & 1;
    (p ? lgP2f : lgP1f)[(((size_t)l * 64 + bb) * 16 + c) * 2 + hf] = val;
  }
}

// ---------------- K3: e2 pass, block-staged tiles, both branches (z) ----------------
__global__ __launch_bounds__(256, 4) void k_out(
    const unsigned short* __restrict__ xtb1, const unsigned short* __restrict__ xtb2,
    const unsigned short* __restrict__ f1_rm, const unsigned short* __restrict__ f2_rm,
    const unsigned short* __restrict__ vt2,
    const float* __restrict__ nf1l, const float* __restrict__ nf2l,
    const int* __restrict__ lidxp1, const int* __restrict__ lidxp2,
    const float2* __restrict__ lgP1, const float2* __restrict__ lgP2,
    float* __restrict__ qp1, float* __restrict__ qp2,
    float* __restrict__ qsp1, float* __restrict__ qsp2, int nch)
{
  __shared__ __align__(16) unsigned short sm[4096 + 2048 + 4 * 32 * PSTR];  // A | vt2 | P
  unsigned short* aT = sm;
  unsigned short* vT = sm + 4096;
  const int br = blockIdx.z;
  const unsigned short* xtb = br ? xtb2 : xtb1;
  const unsigned short* f_rm = br ? f2_rm : f1_rm;
  const float* nfl = br ? nf2l : nf1l;
  const int* lidxp = br ? lidxp2 : lidxp1;
  const float2* lgP = br ? lgP2 : lgP1;
  float* qp = br ? qp2 : qp1;
  float* qsp = br ? qsp2 : qsp1;

  const int tid = threadIdx.x;
  const int w = tid >> 6, lane = tid & 63;
  const int col = lane & 15, quad = lane >> 4;
  const int x0s = quad ^ (col & 7);
  const int x1s = x0s ^ 4;
  unsigned short* myp = sm + 4096 + 2048 + w * (32 * PSTR);
  const int b0 = blockIdx.x * 128 + w * 32;
  const int bb = blockIdx.x * 4 + w;
  const int k = blockIdx.y;
  const int t0 = (k * NT) / nch, t1 = ((k + 1) * NT) / nch;

  bfrag xq00 = *(const bfrag*)(xtb + (size_t)(b0 + col) * DD + quad * 8);
  bfrag xq01 = *(const bfrag*)(xtb + (size_t)(b0 + col) * DD + 32 + quad * 8);
  bfrag xq10 = *(const bfrag*)(xtb + (size_t)(b0 + 16 + col) * DD + quad * 8);
  bfrag xq11 = *(const bfrag*)(xtb + (size_t)(b0 + 16 + col) * DD + 32 + quad * 8);

  ffrag acc[2][2];
#pragma unroll
  for (int n = 0; n < 2; n++) {
    acc[n][0] = (ffrag){0.f, 0.f, 0.f, 0.f};
    acc[n][1] = (ffrag){0.f, 0.f, 0.f, 0.f};
  }
  float es0 = 0.f, es1 = 0.f;

  for (int t = t0; t < t1; ++t) {
    const int i0 = t * 64;
    // ---- stage: A 2 instr/wave, vt2 1 instr/wave ----
#pragma unroll
    for (int j = 0; j < 2; j++) {
      int S = ((w * 2 + j) << 6) + lane;
      int r = S >> 3, cs = S & 7;
      GLOAD_LDS(f_rm + (size_t)(i0 + r) * DD + ((cs ^ (r & 7)) << 3),
                aT + ((w * 2 + j) << 9));
    }
    {
      int S = (w << 6) + lane;
      int r = S >> 3, cs = S & 7;
      GLOAD_LDS(vt2 + (size_t)r * NSP + i0 + ((cs ^ (r & 7)) << 3),
                vT + (w << 9));
    }
    __syncthreads();
    // ---- G1 + eld gather + exp + P-write ----
#pragma unroll
    for (int m = 0; m < 4; m++) {
      const int row = m * 16 + col;
      int4 lv = *(const int4*)(lidxp + i0 + m * 16 + quad * 4);
      float2 g0v = lgP[((size_t)lv.x * 64 + bb) * 16 + col];
      float2 g1v = lgP[((size_t)lv.y * 64 + bb) * 16 + col];
      float2 g2v = lgP[((size_t)lv.z * 64 + bb) * 16 + col];
      float2 g3v = lgP[((size_t)lv.w * 64 + bb) * 16 + col];
      bfrag a0 = *(const bfrag*)(aT + row * 64 + x0s * 8);
      bfrag a1 = *(const bfrag*)(aT + row * 64 + x1s * 8);
      ffrag c0 = (ffrag){0.f, 0.f, 0.f, 0.f};
      ffrag c1 = (ffrag){0.f, 0.f, 0.f, 0.f};
      c0 = MFMA(a0, xq00, c0, 0, 0, 0); c0 = MFMA(a1, xq01, c0, 0, 0, 0);
      c1 = MFMA(a0, xq10, c1, 0, 0, 0); c1 = MFMA(a1, xq11, c1, 0, 0, 0);
      float4 nfv = *(const float4*)(nfl + i0 + m * 16 + quad * 4);
      float ea0 = EXP2(c0[0] - nfv.x + g0v.x), eb0 = EXP2(c1[0] - nfv.x + g0v.y);
      float ea1 = EXP2(c0[1] - nfv.y + g1v.x), eb1 = EXP2(c1[1] - nfv.y + g1v.y);
      float ea2 = EXP2(c0[2] - nfv.z + g2v.x), eb2 = EXP2(c1[2] - nfv.z + g2v.y);
      float ea3 = EXP2(c0[3] - nfv.w + g3v.x), eb3 = EXP2(c1[3] - nfv.w + g3v.y);
      es0 += ea0 + ea1 + ea2 + ea3;
      es1 += eb0 + eb1 + eb2 + eb3;
      *(uint2*)(myp + col * PSTR + m * 16 + quad * 4) =
          make_uint2((unsigned)bf16rne(ea0) | ((unsigned)bf16rne(ea1) << 16),
                     (unsigned)bf16rne(ea2) | ((unsigned)bf16rne(ea3) << 16));
      *(uint2*)(myp + (col + 16) * PSTR + m * 16 + quad * 4) =
          make_uint2((unsigned)bf16rne(eb0) | ((unsigned)bf16rne(eb1) << 16),
                     (unsigned)bf16rne(eb2) | ((unsigned)bf16rne(eb3) << 16));
    }
    // ---- P-read + G2 from staged vt2 ----
    bfrag pa0 = *(const bfrag*)(myp + col * PSTR + quad * 8);
    bfrag pa1 = *(const bfrag*)(myp + col * PSTR + 32 + quad * 8);
    bfrag pb0 = *(const bfrag*)(myp + (col + 16) * PSTR + quad * 8);
    bfrag pb1 = *(const bfrag*)(myp + (col + 16) * PSTR + 32 + quad * 8);
#pragma unroll
    for (int n = 0; n < 2; n++) {
      const int row = n * 16 + col;
      bfrag v0 = *(const bfrag*)(vT + row * 64 + x0s * 8);
      bfrag v1 = *(const bfrag*)(vT + row * 64 + x1s * 8);
      acc[n][0] = MFMA(pa0, v0, acc[n][0], 0, 0, 0);
      acc[n][0] = MFMA(pa1, v1, acc[n][0], 0, 0, 0);
      acc[n][1] = MFMA(pb0, v0, acc[n][1], 0, 0, 0);
      acc[n][1] = MFMA(pb1, v1, acc[n][1], 0, 0, 0);
    }
    __syncthreads();
  }

#pragma unroll
  for (int h = 0; h < 2; h++)
#pragma unroll
    for (int n = 0; n < 2; n++)
#pragma unroll
      for (int r = 0; r < 4; r++) {
        int b = b0 + h * 16 + quad * 4 + r;
        qp[((size_t)k * NQ + b) * DY + n * 16 + col] = acc[n][h][r];
      }
  es0 += __shfl_xor(es0, 16, 64); es0 += __shfl_xor(es0, 32, 64);
  es1 += __shfl_xor(es1, 16, 64); es1 += __shfl_xor(es1, 32, 64);
  if (quad == 0) {
    qsp[(size_t)k * NQ + b0 + col] = es0;
    qsp[(size_t)k * NQ + b0 + 16 + col] = es1;
  }
}

// ---------------- K4: reduce partials + average ----------------
__global__ __launch_bounds__(256) void k_fin(
    const float* __restrict__ qp1, const float* __restrict__ qsp1,
    const float* __restrict__ qp2, const float* __restrict__ qsp2,
    float* __restrict__ out, int nch)
{
  int t = blockIdx.x * 256 + threadIdx.x;
  if (t >= NQ * DY) return;
  int b = t >> 5, j = t & 31;
  float n1 = 0.f, d1 = 0.f, n2 = 0.f, d2 = 0.f;
  for (int kk = 0; kk < nch; kk++) {
    n1 += qp1[((size_t)kk * NQ + b) * DY + j];
    n2 += qp2[((size_t)kk * NQ + b) * DY + j];
    d1 += qsp1[(size_t)kk * NQ + b];
    d2 += qsp2[(size_t)kk * NQ + b];
  }
  out[t] = 0.5f * (n1 / d1 + n2 / d2);
}

extern "C" void kernel_launch(void* const* d_in, const int* in_sizes, int n_in,
                              void* d_out, int out_size, void* d_ws, size_t ws_size,
                              hipStream_t stream)
{
  const float* x    = (const float*)d_in[0];
  const float* star = (const float*)d_in[1];
  const float* slab = (const float*)d_in[2];
  const float* f1   = (const float*)d_in[3];
  const float* f2   = (const float*)d_in[4];
  const float* u1   = (const float*)d_in[5];
  const float* u2   = (const float*)d_in[6];
  const float* ld1  = (const float*)d_in[7];
  const float* ld2  = (const float*)d_in[8];
  const float* W1   = (const float*)d_in[9];
  const float* b1   = (const float*)d_in[10];
  const float* W2   = (const float*)d_in[11];
  const float* b2   = (const float*)d_in[12];
  const int* lidx1  = (const int*)d_in[13];
  const int* lidx2  = (const int*)d_in[14];
  float* out = (float*)d_out;

  auto al = [](size_t b) { return (b + 255) & ~(size_t)255; };
  const size_t auxBytes =
      al((size_t)NQ * DD * 2) +
      3 * al((size_t)NSP * DD * 2) +
      al((size_t)128 * NSP * 2) +
      al((size_t)32 * NSP * 2) +
      2 * al((size_t)NQ * DD * 2) +
      3 * al((size_t)NSP * 4) +
      al((size_t)NQ * 4) +
      2 * al((size_t)LL * 64 * 16 * 8) +
      2 * al((size_t)NSP * 4) +
      3 * al((size_t)NQ * 4);
  const size_t pc1 = (size_t)NQ * 4 * 129;
  const size_t pc2 = (size_t)NQ * 4 * 2 * (DY + 1);
  int nch1 = 48, nch2 = 48;
  while ((nch1 > 6) && auxBytes + nch1 * pc1 + nch2 * pc2 > ws_size) {
    nch1 >>= 1;
    if (nch2 > 6) nch2 >>= 1;
  }

  char* base = (char*)d_ws;
  size_t off = 0;
  auto alloc = [&](size_t bytes) -> char* {
    char* p = base + off;
    off = (off + bytes + 255) & ~(size_t)255;
    return p;
  };
  float* xtp  = (float*)alloc((size_t)nch1 * NQ * 128 * 4);
  float* sump = (float*)alloc((size_t)nch1 * NQ * 4);
  float* qp1  = (float*)alloc((size_t)nch2 * NQ * DY * 4);
  float* qp2  = (float*)alloc((size_t)nch2 * NQ * DY * 4);
  float* qsp1 = (float*)alloc((size_t)nch2 * NQ * 4);
  float* qsp2 = (float*)alloc((size_t)nch2 * NQ * 4);
  unsigned short* xb     = (unsigned short*)alloc((size_t)NQ * DD * 2);
  unsigned short* star_b = (unsigned short*)alloc((size_t)NSP * DD * 2);
  unsigned short* f1_rm  = (unsigned short*)alloc((size_t)NSP * DD * 2);
  unsigned short* f2_rm  = (unsigned short*)alloc((size_t)NSP * DD * 2);
  unsigned short* vt1    = (unsigned short*)alloc((size_t)128 * NSP * 2);
  unsigned short* vt2    = (unsigned short*)alloc((size_t)32 * NSP * 2);
  unsigned short* xtb1   = (unsigned short*)alloc((size_t)NQ * DD * 2);
  unsigned short* xtb2   = (unsigned short*)alloc((size_t)NQ * DD * 2);
  float* nsl   = (float*)alloc(NSP * 4);
  float* nf1l  = (float*)alloc(NSP * 4);
  float* nf2l  = (float*)alloc(NSP * 4);
  float* nxl   = (float*)alloc(NQ * 4);
  float2* lgP1 = (float2*)alloc((size_t)LL * 64 * 16 * 8);
  float2* lgP2 = (float2*)alloc((size_t)LL * 64 * 16 * 8);
  int* lidxp1 = (int*)alloc(NSP * 4);
  int* lidxp2 = (int*)alloc(NSP * 4);
  int* matchIdx = (int*)alloc(NQ * 4);
  int* yid1 = (int*)alloc(NQ * 4);
  int* yid2 = (int*)alloc(NQ * 4);

  k_prep<<<NT + (NQ + 255) / 256, 256, 0, stream>>>(
      star, f1, f2, slab, x, lidx1, lidx2,
      star_b, f1_rm, f2_rm, vt1, vt2, xb,
      nsl, nf1l, nf2l, nxl, lidxp1, lidxp2, matchIdx);

  k_star<<<dim3(NQ / 128, nch1), 256, 0, stream>>>(
      xb, star_b, vt1, nsl, nxl, xtp, sump, matchIdx, nch1);

  k_mid<<<NQ / 4, 256, 0, stream>>>(
      xtp, sump, matchIdx, f1, f2, W1, b1, W2, b2, u1, u2, ld1, ld2,
      xtb1, xtb2, yid1, yid2, (float*)lgP1, (float*)lgP2, nch1);

  k_out<<<dim3(NQ / 128, nch2, 2), 256, 0, stream>>>(
      xtb1, xtb2, f1_rm, f2_rm, vt2, nf1l, nf2l, lidxp1, lidxp2,
      lgP1, lgP2, qp1, qp2, qsp1, qsp2, nch2);

  k_fin<<<(NQ * DY + 255) / 256, 256, 0, stream>>>(qp1, qsp1, qp2, qsp2, out, nch2);
}